// Round 17
// baseline (116.543 us; speedup 1.0000x reference)
//
#include <hip/hip_runtime.h>
#include <stdint.h>
#include <math.h>

typedef unsigned int u32;
typedef unsigned long long u64;
typedef unsigned char u8;

#define BB 8
#define AA 19206
#define CCH 91
#define NCLS 90
#define KSEL 256
#define MAXDET 100
#define NROWS (BB*NCLS)      // 720
#define NFLAT (NCLS*MAXDET)  // 9000
#define IOU_T 0.6f

// ---------------- sigmoid + transpose (+ u8 bin sidecar) ----------------
#define ATILE 64
__global__ void __launch_bounds__(256) k_sigT(const float* __restrict__ logits,
    float* __restrict__ sc, u8* __restrict__ sbin, int b0) {
  __shared__ __align__(16) float tile[ATILE * CCH];  // 23.3 KB
  int bl = blockIdx.y;            // local batch within chunk
  int b  = b0 + bl;               // global batch
  int a0 = blockIdx.x * ATILE;
  int nt = AA - a0; if (nt > ATILE) nt = ATILE;
  int nload = nt * CCH;           // even
  const float* src = logits + ((size_t)b * AA + a0) * CCH;   // 8B aligned
  const float2* s2 = (const float2*)src;
  int n2 = nload >> 1;
  for (int i = threadIdx.x; i < n2; i += 256) ((float2*)tile)[i] = s2[i];
  __syncthreads();
  for (int j = threadIdx.x; j < ATILE * NCLS; j += 256) {
    int c  = j >> 6;       // whole wave shares c -> coalesced store
    int ai = j & 63;
    if (ai < nt) {
      float x = tile[ai * CCH + (c + 1)];
      float s = 1.0f / (1.0f + expf(-x));
      size_t o = ((size_t)bl * NCLS + c) * AA + a0 + ai;
      sc[o] = s;
      sbin[o] = (u8)min(255, (int)(s * 256.0f));
    }
  }
}

// ---------------- per-row top-256: u8-hist pass + compact+sort pass --------
__global__ void __launch_bounds__(512) k_row(const float* __restrict__ sc,
    const u8* __restrict__ sbin,
    float* __restrict__ tks, int* __restrict__ tki, int row0) {
  __shared__ u32 hist[256];
  __shared__ u32 suf[256];
  __shared__ u64 cand[512];
  __shared__ int shBs, ctr;
  int rl  = blockIdx.x;
  int row = row0 + rl;
  int tid = threadIdx.x;
  const float2* src = (const float2*)(sc + (size_t)rl * AA);     // AA even
  const uchar2* sb2 = (const uchar2*)(sbin + (size_t)rl * AA);   // 2B aligned
  if (tid < 256) hist[tid] = 0;
  if (tid == 0) ctr = 0;
  __syncthreads();
  // pass 1: histogram from u8 sidecar (1/4 the bytes of the f32 row)
  for (int i = tid; i < AA / 2; i += 512) {
    uchar2 bb = sb2[i];
    atomicAdd(&hist[bb.x], 1u);
    atomicAdd(&hist[bb.y], 1u);
  }
  __syncthreads();
  if (tid < 256) suf[tid] = hist[tid];
  __syncthreads();
  for (int off = 1; off < 256; off <<= 1) {
    u32 v = 0;
    if (tid < 256 && tid + off < 256) v = suf[tid + off];
    __syncthreads();
    if (tid < 256) suf[tid] += v;
    __syncthreads();
  }
  if (tid < 256) {
    u32 nxt = (tid < 255) ? suf[tid + 1] : 0u;
    if (suf[tid] >= (u32)KSEL && nxt < (u32)KSEL) shBs = tid;
  }
  __syncthreads();
  int Bs = shBs;
  int lane = tid & 63;
  // pass 2: L2/L3-hot f32 read; bin recomputed from identical stored s
  for (int i = tid; i < AA / 2; i += 512) {
    float2 v = src[i];
    {
      bool p = min(255, (int)(v.x * 256.0f)) >= Bs;
      u64 m = __ballot(p);
      if (p) {
        int leader = (int)(__ffsll((long long)m) - 1);
        int base = 0;
        if (lane == leader) base = atomicAdd(&ctr, (int)__popcll(m));
        base = __shfl(base, leader);
        int pos = base + (int)__popcll(m & ((1ull << lane) - 1ull));
        if (pos < 512)
          cand[pos] = ((u64)__float_as_uint(v.x) << 32) | (u32)(~(u32)(2 * i));
      }
    }
    {
      bool p = min(255, (int)(v.y * 256.0f)) >= Bs;
      u64 m = __ballot(p);
      if (p) {
        int leader = (int)(__ffsll((long long)m) - 1);
        int base = 0;
        if (lane == leader) base = atomicAdd(&ctr, (int)__popcll(m));
        base = __shfl(base, leader);
        int pos = base + (int)__popcll(m & ((1ull << lane) - 1ull));
        if (pos < 512)
          cand[pos] = ((u64)__float_as_uint(v.y) << 32) | (u32)(~(u32)(2 * i + 1));
      }
    }
  }
  __syncthreads();
  int n = ctr < 512 ? ctr : 512;
  for (int i = n + tid; i < 512; i += 512) cand[i] = 0;  // pad sorts low
  __syncthreads();
  // bitonic sort 512 ascending, 1 element per thread
  for (int k = 2; k <= 512; k <<= 1) {
    for (int j = k >> 1; j > 0; j >>= 1) {
      int l = tid ^ j;
      if (l > tid) {
        u64 x = cand[tid], y = cand[l];
        bool asc = ((tid & k) == 0);
        if ((x > y) == asc) { cand[tid] = y; cand[l] = x; }
      }
      __syncthreads();
    }
  }
  if (tid < KSEL) {
    u64 kk = cand[511 - tid];
    tks[(size_t)row * KSEL + tid] = __uint_as_float((u32)(kk >> 32));
    tki[(size_t)row * KSEL + tid] = (int)(~(u32)kk);
  }
}

// ---------------- helpers ----------------
__device__ inline float rdlane(float x, int l) {
  return __int_as_float(__builtin_amdgcn_readlane(__float_as_int(x), l));
}

__device__ inline float4 decode1(const float* __restrict__ enc,
                                 const float* __restrict__ anch, int b, int ai) {
  float4 e  = ((const float4*)enc)[(size_t)b * AA + ai];
  float4 an = ((const float4*)anch)[ai];
  float ty = e.x / 10.0f, tx = e.y / 10.0f, th = e.z / 5.0f, tw = e.w / 5.0f;
  float yc = ty * an.z + an.x;
  float xc = tx * an.w + an.y;
  float h  = expf(th) * an.z;
  float w  = expf(tw) * an.w;
  float4 o;
  o.x = yc - h * 0.5f; o.y = xc - w * 0.5f; o.z = yc + h * 0.5f; o.w = xc + w * 0.5f;
  return o;
}

// ---------------- NMS v7: sorted-scan, 2 speculative emits per iteration ---
// Exact: w2 = next alive after w1 (pre-update). All positions < w2 except w1
// were already dead, and suppression only kills -> if w2 survives w1's
// suppression test (same exact per-pair compare), w2 IS the next argmax.
__global__ void __launch_bounds__(256) k_nms(const float* __restrict__ enc,
    const float* __restrict__ anch,
    const float* __restrict__ tks, const int* __restrict__ tki,
    float* __restrict__ flat_s, float* __restrict__ flat_b) {
  int wid = threadIdx.x >> 6, lane = threadIdx.x & 63;
  int row = blockIdx.x * 4 + wid;
  int b = row / NCLS, c = row % NCLS;
  const float* trow = tks + (size_t)row * KSEL;
  const int*   irow = tki + (size_t)row * KSEL;
  float s0 = trow[lane], s1 = trow[64 + lane], s2 = trow[128 + lane], s3 = trow[192 + lane];
  int   i0 = irow[lane], i1 = irow[64 + lane], i2 = irow[128 + lane], i3 = irow[192 + lane];
  float4 B0 = decode1(enc, anch, b, i0);
  float4 B1 = decode1(enc, anch, b, i1);
  float4 B2 = decode1(enc, anch, b, i2);
  float4 B3 = decode1(enc, anch, b, i3);
  float a0 = (B0.z - B0.x) * (B0.w - B0.y);
  float a1 = (B1.z - B1.x) * (B1.w - B1.y);
  float a2 = (B2.z - B2.x) * (B2.w - B2.y);
  float a3 = (B3.z - B3.x) * (B3.w - B3.y);
  u64 m0 = __ballot(s0 > 0.0f);
  u64 m1 = __ballot(s1 > 0.0f);
  u64 m2 = __ballot(s2 > 0.0f);
  u64 m3 = __ballot(s3 > 0.0f);
  // exact threshold midpoint: RN(q) >= 0.6f  <=>  q >= M
  const float cP = __uint_as_float(0x3F199999u);   // pred(0.6f)
  const double M = 0.5 * ((double)cP + (double)0.6f);
  float ss0 = 0.0f, ss1 = 0.0f;
  float4 ob0; ob0.x = ob0.y = ob0.z = ob0.w = 0.0f;
  float4 ob1 = ob0;
  size_t fo = (size_t)b * NFLAT + (size_t)c * MAXDET;
  int d = 0;
  while (d < MAXDET) {
    // ---- select w1 = first alive ----
    int kw1; u64 w;
    if      (m0) { kw1 = 0; w = m0; }
    else if (m1) { kw1 = 1; w = m1; }
    else if (m2) { kw1 = 2; w = m2; }
    else if (m3) { kw1 = 3; w = m3; }
    else break;
    int lw1 = (int)__builtin_ctzll(w);
    u64 bit1 = 1ull << lw1;
    // ---- select w2 = next alive with w1 cleared ----
    u64 q0 = (kw1 == 0) ? (m0 & ~bit1) : m0;
    u64 q1 = (kw1 == 1) ? (m1 & ~bit1) : m1;
    u64 q2 = (kw1 == 2) ? (m2 & ~bit1) : m2;
    u64 q3 = (kw1 == 3) ? (m3 & ~bit1) : m3;
    bool has2 = (q0 | q1 | q2 | q3) != 0ull;
    int kw2; u64 w2w;
    if      (q0) { kw2 = 0; w2w = q0; }
    else if (q1) { kw2 = 1; w2w = q1; }
    else if (q2) { kw2 = 2; w2w = q2; }
    else         { kw2 = 3; w2w = q3 ? q3 : 1ull; }
    int lw2 = (int)__builtin_ctzll(w2w);
    // ---- fetch both winners (branchless k-select + readlane) ----
    float cs1 = (kw1 == 0) ? s0   : (kw1 == 1) ? s1   : (kw1 == 2) ? s2   : s3;
    float cx1 = (kw1 == 0) ? B0.x : (kw1 == 1) ? B1.x : (kw1 == 2) ? B2.x : B3.x;
    float cy1 = (kw1 == 0) ? B0.y : (kw1 == 1) ? B1.y : (kw1 == 2) ? B2.y : B3.y;
    float cz1 = (kw1 == 0) ? B0.z : (kw1 == 1) ? B1.z : (kw1 == 2) ? B2.z : B3.z;
    float cw1 = (kw1 == 0) ? B0.w : (kw1 == 1) ? B1.w : (kw1 == 2) ? B2.w : B3.w;
    float sA = rdlane(cs1, lw1);
    float xA = rdlane(cx1, lw1);
    float yA = rdlane(cy1, lw1);
    float zA = rdlane(cz1, lw1);
    float wA = rdlane(cw1, lw1);
    float cs2 = (kw2 == 0) ? s0   : (kw2 == 1) ? s1   : (kw2 == 2) ? s2   : s3;
    float cx2 = (kw2 == 0) ? B0.x : (kw2 == 1) ? B1.x : (kw2 == 2) ? B2.x : B3.x;
    float cy2 = (kw2 == 0) ? B0.y : (kw2 == 1) ? B1.y : (kw2 == 2) ? B2.y : B3.y;
    float cz2 = (kw2 == 0) ? B0.z : (kw2 == 1) ? B1.z : (kw2 == 2) ? B2.z : B3.z;
    float cw2 = (kw2 == 0) ? B0.w : (kw2 == 1) ? B1.w : (kw2 == 2) ? B2.w : B3.w;
    float sB = rdlane(cs2, lw2);
    float xB = rdlane(cx2, lw2);
    float yB = rdlane(cy2, lw2);
    float zB = rdlane(cz2, lw2);
    float wB = rdlane(cw2, lw2);
    // ---- both suppression ballot-sets in parallel ----
    float iaA = (zA - xA) * (wA - yA);
    float iaB = (zB - xB) * (wB - yB);
#define PAIR(WX, WY, WZ, WW, IA, BX, AK, INK, UNK) { \
      float ty = fmaxf(WX, BX.x), tx = fmaxf(WY, BX.y); \
      float by = fminf(WZ, BX.z), bw = fminf(WW, BX.w); \
      float hh = fmaxf(by - ty, 0.0f), wvv = fmaxf(bw - tx, 0.0f); \
      INK = hh * wvv; \
      UNK = fmaxf(IA + AK - INK, 1e-8f); }
    float iA0, iA1, iA2, iA3, uA0, uA1, uA2, uA3;
    float iB0, iB1, iB2, iB3, uB0, uB1, uB2, uB3;
    PAIR(xA, yA, zA, wA, iaA, B0, a0, iA0, uA0)
    PAIR(xA, yA, zA, wA, iaA, B1, a1, iA1, uA1)
    PAIR(xA, yA, zA, wA, iaA, B2, a2, iA2, uA2)
    PAIR(xA, yA, zA, wA, iaA, B3, a3, iA3, uA3)
    PAIR(xB, yB, zB, wB, iaB, B0, a0, iB0, uB0)
    PAIR(xB, yB, zB, wB, iaB, B1, a1, iB1, uB1)
    PAIR(xB, yB, zB, wB, iaB, B2, a2, iB2, uB2)
    PAIR(xB, yB, zB, wB, iaB, B3, a3, iB3, uB3)
#undef PAIR
    u64 cA0 = __ballot((double)iA0 >= M * (double)uA0);
    u64 cA1 = __ballot((double)iA1 >= M * (double)uA1);
    u64 cA2 = __ballot((double)iA2 >= M * (double)uA2);
    u64 cA3 = __ballot((double)iA3 >= M * (double)uA3);
    u64 cB0 = __ballot((double)iB0 >= M * (double)uB0);
    u64 cB1 = __ballot((double)iB1 >= M * (double)uB1);
    u64 cB2 = __ballot((double)iB2 >= M * (double)uB2);
    u64 cB3 = __ballot((double)iB3 >= M * (double)uB3);
    // ---- does w2 survive w1's suppression? ----
    u64 cA_k2 = (kw2 == 0) ? cA0 : (kw2 == 1) ? cA1 : (kw2 == 2) ? cA2 : cA3;
    bool commit2 = has2 && (d + 1 < MAXDET) && (((cA_k2 >> lw2) & 1ull) == 0ull);
    // ---- capture w1 at slot d, w2 at slot d+1 ----
    bool c0a = (lane == d);
    bool c1a = (lane + 64 == d);
    ss0 = c0a ? sA : ss0;
    ob0.x = c0a ? xA : ob0.x; ob0.y = c0a ? yA : ob0.y;
    ob0.z = c0a ? zA : ob0.z; ob0.w = c0a ? wA : ob0.w;
    ss1 = c1a ? sA : ss1;
    ob1.x = c1a ? xA : ob1.x; ob1.y = c1a ? yA : ob1.y;
    ob1.z = c1a ? zA : ob1.z; ob1.w = c1a ? wA : ob1.w;
    bool c0b = commit2 && (lane == d + 1);
    bool c1b = commit2 && (lane + 64 == d + 1);
    ss0 = c0b ? sB : ss0;
    ob0.x = c0b ? xB : ob0.x; ob0.y = c0b ? yB : ob0.y;
    ob0.z = c0b ? zB : ob0.z; ob0.w = c0b ? wB : ob0.w;
    ss1 = c1b ? sB : ss1;
    ob1.x = c1b ? xB : ob1.x; ob1.y = c1b ? yB : ob1.y;
    ob1.z = c1b ? zB : ob1.z; ob1.w = c1b ? wB : ob1.w;
    // ---- mask update ----
    m0 &= ~cA0; m1 &= ~cA1; m2 &= ~cA2; m3 &= ~cA3;
    if (commit2) { m0 &= ~cB0; m1 &= ~cB1; m2 &= ~cB2; m3 &= ~cB3; }
    d += 1 + (commit2 ? 1 : 0);
  }
  flat_s[fo + lane] = ss0;
  ((float4*)flat_b)[fo + lane] = ob0;
  if (lane < MAXDET - 64) {
    flat_s[fo + 64 + lane] = ss1;
    ((float4*)flat_b)[fo + 64 + lane] = ob1;
  }
}

// ---------------- bitonic sorts (block of 256 threads) ----------------
__device__ inline void bitonic_u64_asc(u64* a, int n, int tid) {
  for (int k = 2; k <= n; k <<= 1) {
    for (int j = k >> 1; j > 0; j >>= 1) {
      for (int i = tid; i < n; i += 256) {
        int l = i ^ j;
        if (l > i) {
          u64 x = a[i], y = a[l];
          bool asc = ((i & k) == 0);
          if ((x > y) == asc) { a[i] = y; a[l] = x; }
        }
      }
      __syncthreads();
    }
  }
}
__device__ inline void bitonic_u32_asc(u32* a, int n, int tid) {
  for (int k = 2; k <= n; k <<= 1) {
    for (int j = k >> 1; j > 0; j >>= 1) {
      for (int i = tid; i < n; i += 256) {
        int l = i ^ j;
        if (l > i) {
          u32 x = a[i], y = a[l];
          bool asc = ((i & k) == 0);
          if ((x > y) == asc) { a[i] = y; a[l] = x; }
        }
      }
      __syncthreads();
    }
  }
}

// ---------------- exact radix select (rank kwant, descending) ----------------
template<typename F>
__device__ inline void radix_select(F getv, int n, int kwant,
    u32* hist, u32* suf, int* sh2, int tid,
    u32& V_out, int& GT_out, int& r_out) {
  int r = kwant; u32 V = 0; int GT = 0;
  for (int lvl = 0; lvl < 3; lvl++) {
    int shift = (lvl == 0) ? 19 : ((lvl == 1) ? 8 : 0);
    int nbins = (lvl == 2) ? 256 : 2048;
    for (int i = tid; i < nbins; i += 256) hist[i] = 0;
    __syncthreads();
    for (int idx = tid; idx < n; idx += 256) {
      u32 u = __float_as_uint(getv(idx));
      bool ok = (lvl == 0) || (lvl == 1 ? ((u >> 19) == (V >> 19))
                                        : ((u >> 8)  == (V >> 8)));
      u64 zm = __ballot(ok && u == 0u);
      if (ok) {
        if (u == 0u) {
          if ((int)(threadIdx.x & 63) == (int)(__ffsll((long long)zm) - 1))
            atomicAdd(&hist[0], (u32)__popcll(zm));
        } else {
          atomicAdd(&hist[(u >> shift) & (u32)(nbins - 1)], 1u);
        }
      }
    }
    __syncthreads();
    int G = nbins >> 8;
    u32 ps = 0;
    for (int g = 0; g < G; g++) ps += hist[tid * G + g];
    suf[tid] = ps;
    __syncthreads();
    for (int off = 1; off < 256; off <<= 1) {
      u32 v = (tid + off < 256) ? suf[tid + off] : 0u;
      __syncthreads();
      suf[tid] += v;
      __syncthreads();
    }
    u32 sufnext = (tid < 255) ? suf[tid + 1] : 0u;
    if (suf[tid] >= (u32)r && sufnext < (u32)r) {
      u32 cum = sufnext; int kb = tid * G;
      for (int bin = tid * G + G - 1; bin >= tid * G; bin--) {
        cum += hist[bin];
        if (cum >= (u32)r) { kb = bin; break; }
      }
      sh2[0] = kb;
      sh2[1] = (int)(cum - hist[kb]);
    }
    __syncthreads();
    int kb = sh2[0], gt = sh2[1];
    r -= gt; GT += gt; V |= ((u32)kb) << shift;
    __syncthreads();
  }
  V_out = V; GT_out = GT; r_out = r;
}

// ---------------- fallback: direct strided top-256 (small ws only) ----------
__global__ void __launch_bounds__(256) k_topk_direct(const float* __restrict__ src,
    float* __restrict__ tks, int* __restrict__ tki) {
  __shared__ u32 hist[2048];
  __shared__ u32 suf[256];
  __shared__ int sh2[2];
  __shared__ u64 sel[KSEL];
  __shared__ u32 tie[512];
  __shared__ int cgt, ctie;
  int row = blockIdx.x, tid = threadIdx.x;
  int b = row / NCLS, c = row % NCLS;
  const float* base = src + (size_t)b * AA * CCH + (c + 1);
  auto getv = [&](int i) -> float {
    float x = base[(size_t)i * CCH]; return 1.0f / (1.0f + expf(-x));
  };
  u32 V; int GT, r;
  radix_select(getv, AA, KSEL, hist, suf, sh2, tid, V, GT, r);
  if (tid == 0) { cgt = 0; ctie = 0; }
  __syncthreads();
  for (int i = tid; i < AA; i += 256) {
    u32 u = __float_as_uint(getv(i));
    if (u > V) {
      int p = atomicAdd(&cgt, 1);
      sel[p] = ((u64)u << 32) | (u32)(~(u32)i);
    } else if (u == V) {
      int p = atomicAdd(&ctie, 1);
      if (p < 512) tie[p] = (u32)i;
    }
  }
  __syncthreads();
  int nt = ctie < 512 ? ctie : 512;
  for (int i = tid + nt; i < 512; i += 256) tie[i] = 0xFFFFFFFFu;
  __syncthreads();
  bitonic_u32_asc(tie, 512, tid);
  for (int i = tid; i < r; i += 256)
    sel[GT + i] = ((u64)V << 32) | (u32)(~tie[i]);
  __syncthreads();
  bitonic_u64_asc(sel, KSEL, tid);
  for (int j = tid; j < KSEL; j += 256) {
    u64 kk = sel[KSEL - 1 - j];
    tks[(size_t)row * KSEL + j] = __uint_as_float((u32)(kk >> 32));
    tki[(size_t)row * KSEL + j] = (int)(~(u32)kk);
  }
}

// ---------------- final per-batch top-100: arith-bin + single sort ---------
__global__ void __launch_bounds__(512) k_final(const float* __restrict__ flat_s,
    const float* __restrict__ flat_b, float* __restrict__ out) {
  __shared__ u32 hist[256];
  __shared__ u32 suf[256];
  __shared__ u64 cand[512];
  __shared__ int shBs, ctr;
  int b = blockIdx.x, tid = threadIdx.x;
  int lane = tid & 63;
  const float2* src = (const float2*)(flat_s + (size_t)b * NFLAT);  // 9000 even
  if (tid < 256) hist[tid] = 0;
  if (tid == 0) ctr = 0;
  __syncthreads();
  for (int i = tid; i < NFLAT / 2; i += 512) {
    float2 v = src[i];
    atomicAdd(&hist[min(255, (int)(v.x * 256.0f))], 1u);
    atomicAdd(&hist[min(255, (int)(v.y * 256.0f))], 1u);
  }
  __syncthreads();
  if (tid < 256) suf[tid] = hist[tid];
  __syncthreads();
  for (int off = 1; off < 256; off <<= 1) {
    u32 v = 0;
    if (tid < 256 && tid + off < 256) v = suf[tid + off];
    __syncthreads();
    if (tid < 256) suf[tid] += v;
    __syncthreads();
  }
  if (tid < 256) {
    u32 nxt = (tid < 255) ? suf[tid + 1] : 0u;
    if (suf[tid] >= (u32)MAXDET && nxt < (u32)MAXDET) shBs = tid;
  }
  __syncthreads();
  int Bs = shBs;
  for (int i = tid; i < NFLAT / 2; i += 512) {
    float2 v = src[i];
    {
      bool p = min(255, (int)(v.x * 256.0f)) >= Bs;
      u64 m = __ballot(p);
      if (p) {
        int leader = (int)(__ffsll((long long)m) - 1);
        int base = 0;
        if (lane == leader) base = atomicAdd(&ctr, (int)__popcll(m));
        base = __shfl(base, leader);
        int pos = base + (int)__popcll(m & ((1ull << lane) - 1ull));
        if (pos < 512)
          cand[pos] = ((u64)__float_as_uint(v.x) << 32) | (u32)(~(u32)(2 * i));
      }
    }
    {
      bool p = min(255, (int)(v.y * 256.0f)) >= Bs;
      u64 m = __ballot(p);
      if (p) {
        int leader = (int)(__ffsll((long long)m) - 1);
        int base = 0;
        if (lane == leader) base = atomicAdd(&ctr, (int)__popcll(m));
        base = __shfl(base, leader);
        int pos = base + (int)__popcll(m & ((1ull << lane) - 1ull));
        if (pos < 512)
          cand[pos] = ((u64)__float_as_uint(v.y) << 32) | (u32)(~(u32)(2 * i + 1));
      }
    }
  }
  __syncthreads();
  int n = ctr < 512 ? ctr : 512;
  for (int i = n + tid; i < 512; i += 512) cand[i] = 0;  // pad sorts low
  __syncthreads();
  for (int k = 2; k <= 512; k <<= 1) {
    for (int j = k >> 1; j > 0; j >>= 1) {
      int l = tid ^ j;
      if (l > tid) {
        u64 x = cand[tid], y = cand[l];
        bool asc = ((tid & k) == 0);
        if ((x > y) == asc) { cand[tid] = y; cand[l] = x; }
      }
      __syncthreads();
    }
  }
  if (tid < MAXDET) {
    u64 kk = cand[511 - tid];
    u32 u  = (u32)(kk >> 32);
    int fi = (int)(~(u32)kk);
    float4 bb = ((const float4*)flat_b)[(size_t)b * NFLAT + fi];
    float* o = out + ((size_t)b * MAXDET + tid) * 6;
    o[0] = bb.x; o[1] = bb.y; o[2] = bb.z; o[3] = bb.w;
    o[4] = (float)(fi / 100 + 1);
    o[5] = __uint_as_float(u);
  }
}

// ---------------- launch ----------------
extern "C" void kernel_launch(void* const* d_in, const int* in_sizes, int n_in,
                              void* d_out, int out_size, void* d_ws, size_t ws_size,
                              hipStream_t stream) {
  const float* enc    = (const float*)d_in[0];
  const float* logits = (const float*)d_in[1];
  const float* anch   = (const float*)d_in[2];
  float* out = (float*)d_out;
  char* ws = (char*)d_ws;

  size_t off = 0;
  auto alloc = [&](size_t bytes) {
    size_t o = off;
    off += (bytes + 255) & ~(size_t)255;
    return o;
  };
  size_t o_tks  = alloc((size_t)NROWS * KSEL * 4);
  size_t o_tki  = alloc((size_t)NROWS * KSEL * 4);
  size_t o_fls  = alloc((size_t)BB * NFLAT * 4);
  size_t o_flb  = alloc((size_t)BB * NFLAT * 16);
  size_t need_base = off;
  size_t o_sc = off;                                   // chunked sc+sbin here
  size_t per_batch_sc   = ((size_t)NCLS * AA * 4 + 255) & ~(size_t)255; // 6.92 MB
  size_t per_batch_sbin = ((size_t)NCLS * AA + 255) & ~(size_t)255;     // 1.73 MB

  int CB = 0;
  for (int cb = BB; cb >= 1; cb >>= 1) {
    if (ws_size >= need_base + (size_t)cb * (per_batch_sc + per_batch_sbin)) {
      CB = cb; break;
    }
  }

  float* tks = (float*)(ws + o_tks);
  int*   tki = (int*)  (ws + o_tki);
  float* fls = (float*)(ws + o_fls);
  float* flb = (float*)(ws + o_flb);
  float* scp = (float*)(ws + o_sc);
  u8*    sbp = (u8*)   (ws + o_sc + (size_t)CB * per_batch_sc);

  if (CB > 0) {
    for (int b0 = 0; b0 < BB; b0 += CB) {
      hipLaunchKernelGGL(k_sigT, dim3((AA + ATILE - 1) / ATILE, CB), dim3(256), 0,
                         stream, logits, scp, sbp, b0);
      hipLaunchKernelGGL(k_row, dim3(NCLS * CB), dim3(512), 0, stream,
                         scp, sbp, tks, tki, b0 * NCLS);
    }
  } else {
    hipLaunchKernelGGL(k_topk_direct, dim3(NROWS), dim3(256), 0, stream,
                       logits, tks, tki);
  }
  hipLaunchKernelGGL(k_nms, dim3(NROWS / 4), dim3(256), 0, stream,
                     enc, anch, tks, tki, fls, flb);
  hipLaunchKernelGGL(k_final, dim3(BB), dim3(512), 0, stream,
                     fls, flb, out);
}

// Round 19
// 112.229 us; speedup vs baseline: 1.0384x; 1.0384x over previous
//
#include <hip/hip_runtime.h>
#include <stdint.h>
#include <math.h>

typedef unsigned int u32;
typedef unsigned long long u64;

#define BB 8
#define AA 19206
#define CCH 91
#define NCLS 90
#define KSEL 256
#define MAXDET 100
#define NROWS (BB*NCLS)      // 720
#define NFLAT (NCLS*MAXDET)  // 9000
#define IOU_T 0.6f

// ---------------- sigmoid + transpose (per batch-chunk) ----------------
#define ATILE 64
__global__ void __launch_bounds__(256) k_sigT(const float* __restrict__ logits,
                                              float* __restrict__ sc, int b0) {
  __shared__ __align__(16) float tile[ATILE * CCH];  // 23.3 KB
  int bl = blockIdx.y;            // local batch within chunk
  int b  = b0 + bl;               // global batch
  int a0 = blockIdx.x * ATILE;
  int nt = AA - a0; if (nt > ATILE) nt = ATILE;
  int nload = nt * CCH;           // even
  const float* src = logits + ((size_t)b * AA + a0) * CCH;   // 8B aligned
  const float2* s2 = (const float2*)src;
  int n2 = nload >> 1;
  for (int i = threadIdx.x; i < n2; i += 256) ((float2*)tile)[i] = s2[i];
  __syncthreads();
  for (int j = threadIdx.x; j < ATILE * NCLS; j += 256) {
    int c  = j >> 6;       // whole wave shares c -> coalesced store
    int ai = j & 63;
    if (ai < nt) {
      float x = tile[ai * CCH + (c + 1)];
      float s = 1.0f / (1.0f + expf(-x));
      sc[((size_t)bl * NCLS + c) * AA + a0 + ai] = s;
    }
  }
}

// ---------------- per-row top-256: 2 global passes (L3-hot), small LDS ------
__global__ void __launch_bounds__(512) k_row(const float* __restrict__ sc,
    float* __restrict__ tks, int* __restrict__ tki, int row0) {
  __shared__ u32 hist[256];
  __shared__ u32 suf[256];
  __shared__ u64 cand[512];
  __shared__ int shBs, ctr;
  int rl  = blockIdx.x;
  int row = row0 + rl;
  int tid = threadIdx.x;
  const float2* src = (const float2*)(sc + (size_t)rl * AA);  // AA even
  if (tid < 256) hist[tid] = 0;
  if (tid == 0) ctr = 0;
  __syncthreads();
  for (int i = tid; i < AA / 2; i += 512) {
    float2 v = src[i];
    atomicAdd(&hist[min(255, (int)(v.x * 256.0f))], 1u);  // monotone bin
    atomicAdd(&hist[min(255, (int)(v.y * 256.0f))], 1u);
  }
  __syncthreads();
  if (tid < 256) suf[tid] = hist[tid];
  __syncthreads();
  for (int off = 1; off < 256; off <<= 1) {
    u32 v = 0;
    if (tid < 256 && tid + off < 256) v = suf[tid + off];
    __syncthreads();
    if (tid < 256) suf[tid] += v;
    __syncthreads();
  }
  if (tid < 256) {
    u32 nxt = (tid < 255) ? suf[tid + 1] : 0u;
    if (suf[tid] >= (u32)KSEL && nxt < (u32)KSEL) shBs = tid;
  }
  __syncthreads();
  int Bs = shBs;
  int lane = tid & 63;
  // pass 2: L2/L3-hot re-read, wave-aggregated LDS append of bins >= Bs
  for (int i = tid; i < AA / 2; i += 512) {
    float2 v = src[i];
    {
      bool p = min(255, (int)(v.x * 256.0f)) >= Bs;
      u64 m = __ballot(p);
      if (p) {
        int leader = (int)(__ffsll((long long)m) - 1);
        int base = 0;
        if (lane == leader) base = atomicAdd(&ctr, (int)__popcll(m));
        base = __shfl(base, leader);
        int pos = base + (int)__popcll(m & ((1ull << lane) - 1ull));
        if (pos < 512)
          cand[pos] = ((u64)__float_as_uint(v.x) << 32) | (u32)(~(u32)(2 * i));
      }
    }
    {
      bool p = min(255, (int)(v.y * 256.0f)) >= Bs;
      u64 m = __ballot(p);
      if (p) {
        int leader = (int)(__ffsll((long long)m) - 1);
        int base = 0;
        if (lane == leader) base = atomicAdd(&ctr, (int)__popcll(m));
        base = __shfl(base, leader);
        int pos = base + (int)__popcll(m & ((1ull << lane) - 1ull));
        if (pos < 512)
          cand[pos] = ((u64)__float_as_uint(v.y) << 32) | (u32)(~(u32)(2 * i + 1));
      }
    }
  }
  __syncthreads();
  int n = ctr < 512 ? ctr : 512;
  for (int i = n + tid; i < 512; i += 512) cand[i] = 0;  // pad sorts low
  __syncthreads();
  // bitonic sort 512 ascending, 1 element per thread
  for (int k = 2; k <= 512; k <<= 1) {
    for (int j = k >> 1; j > 0; j >>= 1) {
      int l = tid ^ j;
      if (l > tid) {
        u64 x = cand[tid], y = cand[l];
        bool asc = ((tid & k) == 0);
        if ((x > y) == asc) { cand[tid] = y; cand[l] = x; }
      }
      __syncthreads();
    }
  }
  if (tid < KSEL) {
    u64 kk = cand[511 - tid];
    tks[(size_t)row * KSEL + tid] = __uint_as_float((u32)(kk >> 32));
    tki[(size_t)row * KSEL + tid] = (int)(~(u32)kk);
  }
}

// ---------------- helpers ----------------
__device__ inline float rdlane(float x, int l) {
  return __int_as_float(__builtin_amdgcn_readlane(__float_as_int(x), l));
}

__device__ inline float4 decode1(const float* __restrict__ enc,
                                 const float* __restrict__ anch, int b, int ai) {
  float4 e  = ((const float4*)enc)[(size_t)b * AA + ai];
  float4 an = ((const float4*)anch)[ai];
  float ty = e.x / 10.0f, tx = e.y / 10.0f, th = e.z / 5.0f, tw = e.w / 5.0f;
  float yc = ty * an.z + an.x;
  float xc = tx * an.w + an.y;
  float h  = expf(th) * an.z;
  float w  = expf(tw) * an.w;
  float4 o;
  o.x = yc - h * 0.5f; o.y = xc - w * 0.5f; o.z = yc + h * 0.5f; o.w = xc + w * 0.5f;
  return o;
}

// ---------------- NMS v4: sorted-scan, exact divide-free IoU test ----------
__global__ void __launch_bounds__(256) k_nms(const float* __restrict__ enc,
    const float* __restrict__ anch,
    const float* __restrict__ tks, const int* __restrict__ tki,
    float* __restrict__ flat_s, float* __restrict__ flat_b) {
  int wid = threadIdx.x >> 6, lane = threadIdx.x & 63;
  int row = blockIdx.x * 4 + wid;
  int b = row / NCLS, c = row % NCLS;
  const float* trow = tks + (size_t)row * KSEL;
  const int*   irow = tki + (size_t)row * KSEL;
  float s0 = trow[lane], s1 = trow[64 + lane], s2 = trow[128 + lane], s3 = trow[192 + lane];
  int   i0 = irow[lane], i1 = irow[64 + lane], i2 = irow[128 + lane], i3 = irow[192 + lane];
  float4 B0 = decode1(enc, anch, b, i0);
  float4 B1 = decode1(enc, anch, b, i1);
  float4 B2 = decode1(enc, anch, b, i2);
  float4 B3 = decode1(enc, anch, b, i3);
  float a0 = (B0.z - B0.x) * (B0.w - B0.y);
  float a1 = (B1.z - B1.x) * (B1.w - B1.y);
  float a2 = (B2.z - B2.x) * (B2.w - B2.y);
  float a3 = (B3.z - B3.x) * (B3.w - B3.y);
  u64 m0 = __ballot(s0 > 0.0f);
  u64 m1 = __ballot(s1 > 0.0f);
  u64 m2 = __ballot(s2 > 0.0f);
  u64 m3 = __ballot(s3 > 0.0f);
  // exact threshold midpoint: RN(q) >= 0.6f  <=>  q >= M
  const float cP = __uint_as_float(0x3F199999u);   // pred(0.6f)
  const double M = 0.5 * ((double)cP + (double)0.6f);
  float ss0 = 0.0f, ss1 = 0.0f;
  float4 ob0; ob0.x = ob0.y = ob0.z = ob0.w = 0.0f;
  float4 ob1 = ob0;
  size_t fo = (size_t)b * NFLAT + (size_t)c * MAXDET;
  for (int d = 0; d < MAXDET; d++) {
    int kw; u64 w;
    if      (m0) { kw = 0; w = m0; }
    else if (m1) { kw = 1; w = m1; }
    else if (m2) { kw = 2; w = m2; }
    else if (m3) { kw = 3; w = m3; }
    else break;
    int lw = (int)__builtin_ctzll(w);
    float sw_, wx_, wy_, wz_, ww_;
    if (kw == 0) {
      sw_ = rdlane(s0, lw);
      wx_ = rdlane(B0.x, lw); wy_ = rdlane(B0.y, lw);
      wz_ = rdlane(B0.z, lw); ww_ = rdlane(B0.w, lw);
    } else if (kw == 1) {
      sw_ = rdlane(s1, lw);
      wx_ = rdlane(B1.x, lw); wy_ = rdlane(B1.y, lw);
      wz_ = rdlane(B1.z, lw); ww_ = rdlane(B1.w, lw);
    } else if (kw == 2) {
      sw_ = rdlane(s2, lw);
      wx_ = rdlane(B2.x, lw); wy_ = rdlane(B2.y, lw);
      wz_ = rdlane(B2.z, lw); ww_ = rdlane(B2.w, lw);
    } else {
      sw_ = rdlane(s3, lw);
      wx_ = rdlane(B3.x, lw); wy_ = rdlane(B3.y, lw);
      wz_ = rdlane(B3.z, lw); ww_ = rdlane(B3.w, lw);
    }
    // register-buffered output capture (no divergent store)
    bool c0 = (lane == d);
    bool c1 = (lane + 64 == d);
    ss0 = c0 ? sw_ : ss0;
    ob0.x = c0 ? wx_ : ob0.x; ob0.y = c0 ? wy_ : ob0.y;
    ob0.z = c0 ? wz_ : ob0.z; ob0.w = c0 ? ww_ : ob0.w;
    ss1 = c1 ? sw_ : ss1;
    ob1.x = c1 ? wx_ : ob1.x; ob1.y = c1 ? wy_ : ob1.y;
    ob1.z = c1 ? wz_ : ob1.z; ob1.w = c1 ? ww_ : ob1.w;
    float ia = (wz_ - wx_) * (ww_ - wy_);
    float in0, in1, in2, in3, un0, un1, un2, un3;
#define PAIR(BX, AK, INK, UNK) { \
      float ty = fmaxf(wx_, BX.x), tx = fmaxf(wy_, BX.y); \
      float by = fminf(wz_, BX.z), bw = fminf(ww_, BX.w); \
      float hh = fmaxf(by - ty, 0.0f), wvv = fmaxf(bw - tx, 0.0f); \
      INK = hh * wvv; \
      UNK = fmaxf(ia + AK - INK, 1e-8f); }
    PAIR(B0, a0, in0, un0)
    PAIR(B1, a1, in1, un1)
    PAIR(B2, a2, in2, un2)
    PAIR(B3, a3, in3, un3)
#undef PAIR
    u64 cm0 = __ballot((double)in0 >= M * (double)un0);
    u64 cm1 = __ballot((double)in1 >= M * (double)un1);
    u64 cm2 = __ballot((double)in2 >= M * (double)un2);
    u64 cm3 = __ballot((double)in3 >= M * (double)un3);
    m0 &= ~cm0; m1 &= ~cm1; m2 &= ~cm2; m3 &= ~cm3;
  }
  flat_s[fo + lane] = ss0;
  ((float4*)flat_b)[fo + lane] = ob0;
  if (lane < MAXDET - 64) {
    flat_s[fo + 64 + lane] = ss1;
    ((float4*)flat_b)[fo + 64 + lane] = ob1;
  }
}

// ---------------- bitonic sorts (block of 256 threads) ----------------
__device__ inline void bitonic_u64_asc(u64* a, int n, int tid) {
  for (int k = 2; k <= n; k <<= 1) {
    for (int j = k >> 1; j > 0; j >>= 1) {
      for (int i = tid; i < n; i += 256) {
        int l = i ^ j;
        if (l > i) {
          u64 x = a[i], y = a[l];
          bool asc = ((i & k) == 0);
          if ((x > y) == asc) { a[i] = y; a[l] = x; }
        }
      }
      __syncthreads();
    }
  }
}
__device__ inline void bitonic_u32_asc(u32* a, int n, int tid) {
  for (int k = 2; k <= n; k <<= 1) {
    for (int j = k >> 1; j > 0; j >>= 1) {
      for (int i = tid; i < n; i += 256) {
        int l = i ^ j;
        if (l > i) {
          u32 x = a[i], y = a[l];
          bool asc = ((i & k) == 0);
          if ((x > y) == asc) { a[i] = y; a[l] = x; }
        }
      }
      __syncthreads();
    }
  }
}

// ---------------- exact radix select (rank kwant, descending) ----------------
template<typename F>
__device__ inline void radix_select(F getv, int n, int kwant,
    u32* hist, u32* suf, int* sh2, int tid,
    u32& V_out, int& GT_out, int& r_out) {
  int r = kwant; u32 V = 0; int GT = 0;
  for (int lvl = 0; lvl < 3; lvl++) {
    int shift = (lvl == 0) ? 19 : ((lvl == 1) ? 8 : 0);
    int nbins = (lvl == 2) ? 256 : 2048;
    for (int i = tid; i < nbins; i += 256) hist[i] = 0;
    __syncthreads();
    for (int idx = tid; idx < n; idx += 256) {
      u32 u = __float_as_uint(getv(idx));
      bool ok = (lvl == 0) || (lvl == 1 ? ((u >> 19) == (V >> 19))
                                        : ((u >> 8)  == (V >> 8)));
      u64 zm = __ballot(ok && u == 0u);
      if (ok) {
        if (u == 0u) {
          if ((int)(threadIdx.x & 63) == (int)(__ffsll((long long)zm) - 1))
            atomicAdd(&hist[0], (u32)__popcll(zm));
        } else {
          atomicAdd(&hist[(u >> shift) & (u32)(nbins - 1)], 1u);
        }
      }
    }
    __syncthreads();
    int G = nbins >> 8;
    u32 ps = 0;
    for (int g = 0; g < G; g++) ps += hist[tid * G + g];
    suf[tid] = ps;
    __syncthreads();
    for (int off = 1; off < 256; off <<= 1) {
      u32 v = (tid + off < 256) ? suf[tid + off] : 0u;
      __syncthreads();
      suf[tid] += v;
      __syncthreads();
    }
    u32 sufnext = (tid < 255) ? suf[tid + 1] : 0u;
    if (suf[tid] >= (u32)r && sufnext < (u32)r) {
      u32 cum = sufnext; int kb = tid * G;
      for (int bin = tid * G + G - 1; bin >= tid * G; bin--) {
        cum += hist[bin];
        if (cum >= (u32)r) { kb = bin; break; }
      }
      sh2[0] = kb;
      sh2[1] = (int)(cum - hist[kb]);
    }
    __syncthreads();
    int kb = sh2[0], gt = sh2[1];
    r -= gt; GT += gt; V |= ((u32)kb) << shift;
    __syncthreads();
  }
  V_out = V; GT_out = GT; r_out = r;
}

// ---------------- fallback: direct strided top-256 (small ws only) ----------
__global__ void __launch_bounds__(256) k_topk_direct(const float* __restrict__ src,
    float* __restrict__ tks, int* __restrict__ tki) {
  __shared__ u32 hist[2048];
  __shared__ u32 suf[256];
  __shared__ int sh2[2];
  __shared__ u64 sel[KSEL];
  __shared__ u32 tie[512];
  __shared__ int cgt, ctie;
  int row = blockIdx.x, tid = threadIdx.x;
  int b = row / NCLS, c = row % NCLS;
  const float* base = src + (size_t)b * AA * CCH + (c + 1);
  auto getv = [&](int i) -> float {
    float x = base[(size_t)i * CCH]; return 1.0f / (1.0f + expf(-x));
  };
  u32 V; int GT, r;
  radix_select(getv, AA, KSEL, hist, suf, sh2, tid, V, GT, r);
  if (tid == 0) { cgt = 0; ctie = 0; }
  __syncthreads();
  for (int i = tid; i < AA; i += 256) {
    u32 u = __float_as_uint(getv(i));
    if (u > V) {
      int p = atomicAdd(&cgt, 1);
      sel[p] = ((u64)u << 32) | (u32)(~(u32)i);
    } else if (u == V) {
      int p = atomicAdd(&ctie, 1);
      if (p < 512) tie[p] = (u32)i;
    }
  }
  __syncthreads();
  int nt = ctie < 512 ? ctie : 512;
  for (int i = tid + nt; i < 512; i += 256) tie[i] = 0xFFFFFFFFu;
  __syncthreads();
  bitonic_u32_asc(tie, 512, tid);
  for (int i = tid; i < r; i += 256)
    sel[GT + i] = ((u64)V << 32) | (u32)(~tie[i]);
  __syncthreads();
  bitonic_u64_asc(sel, KSEL, tid);
  for (int j = tid; j < KSEL; j += 256) {
    u64 kk = sel[KSEL - 1 - j];
    tks[(size_t)row * KSEL + j] = __uint_as_float((u32)(kk >> 32));
    tki[(size_t)row * KSEL + j] = (int)(~(u32)kk);
  }
}

// ---------------- final per-batch top-100: arith-bin + single sort ---------
__global__ void __launch_bounds__(512) k_final(const float* __restrict__ flat_s,
    const float* __restrict__ flat_b, float* __restrict__ out) {
  __shared__ u32 hist[256];
  __shared__ u32 suf[256];
  __shared__ u64 cand[512];
  __shared__ int shBs, ctr;
  int b = blockIdx.x, tid = threadIdx.x;
  int lane = tid & 63;
  const float2* src = (const float2*)(flat_s + (size_t)b * NFLAT);  // 9000 even
  if (tid < 256) hist[tid] = 0;
  if (tid == 0) ctr = 0;
  __syncthreads();
  for (int i = tid; i < NFLAT / 2; i += 512) {
    float2 v = src[i];
    atomicAdd(&hist[min(255, (int)(v.x * 256.0f))], 1u);
    atomicAdd(&hist[min(255, (int)(v.y * 256.0f))], 1u);
  }
  __syncthreads();
  if (tid < 256) suf[tid] = hist[tid];
  __syncthreads();
  for (int off = 1; off < 256; off <<= 1) {
    u32 v = 0;
    if (tid < 256 && tid + off < 256) v = suf[tid + off];
    __syncthreads();
    if (tid < 256) suf[tid] += v;
    __syncthreads();
  }
  if (tid < 256) {
    u32 nxt = (tid < 255) ? suf[tid + 1] : 0u;
    if (suf[tid] >= (u32)MAXDET && nxt < (u32)MAXDET) shBs = tid;
  }
  __syncthreads();
  int Bs = shBs;
  for (int i = tid; i < NFLAT / 2; i += 512) {
    float2 v = src[i];
    {
      bool p = min(255, (int)(v.x * 256.0f)) >= Bs;
      u64 m = __ballot(p);
      if (p) {
        int leader = (int)(__ffsll((long long)m) - 1);
        int base = 0;
        if (lane == leader) base = atomicAdd(&ctr, (int)__popcll(m));
        base = __shfl(base, leader);
        int pos = base + (int)__popcll(m & ((1ull << lane) - 1ull));
        if (pos < 512)
          cand[pos] = ((u64)__float_as_uint(v.x) << 32) | (u32)(~(u32)(2 * i));
      }
    }
    {
      bool p = min(255, (int)(v.y * 256.0f)) >= Bs;
      u64 m = __ballot(p);
      if (p) {
        int leader = (int)(__ffsll((long long)m) - 1);
        int base = 0;
        if (lane == leader) base = atomicAdd(&ctr, (int)__popcll(m));
        base = __shfl(base, leader);
        int pos = base + (int)__popcll(m & ((1ull << lane) - 1ull));
        if (pos < 512)
          cand[pos] = ((u64)__float_as_uint(v.y) << 32) | (u32)(~(u32)(2 * i + 1));
      }
    }
  }
  __syncthreads();
  int n = ctr < 512 ? ctr : 512;
  for (int i = n + tid; i < 512; i += 512) cand[i] = 0;  // pad sorts low
  __syncthreads();
  for (int k = 2; k <= 512; k <<= 1) {
    for (int j = k >> 1; j > 0; j >>= 1) {
      int l = tid ^ j;
      if (l > tid) {
        u64 x = cand[tid], y = cand[l];
        bool asc = ((tid & k) == 0);
        if ((x > y) == asc) { cand[tid] = y; cand[l] = x; }
      }
      __syncthreads();
    }
  }
  if (tid < MAXDET) {
    u64 kk = cand[511 - tid];
    u32 u  = (u32)(kk >> 32);
    int fi = (int)(~(u32)kk);
    float4 bb = ((const float4*)flat_b)[(size_t)b * NFLAT + fi];
    float* o = out + ((size_t)b * MAXDET + tid) * 6;
    o[0] = bb.x; o[1] = bb.y; o[2] = bb.z; o[3] = bb.w;
    o[4] = (float)(fi / 100 + 1);
    o[5] = __uint_as_float(u);
  }
}

// ---------------- launch ----------------
extern "C" void kernel_launch(void* const* d_in, const int* in_sizes, int n_in,
                              void* d_out, int out_size, void* d_ws, size_t ws_size,
                              hipStream_t stream) {
  const float* enc    = (const float*)d_in[0];
  const float* logits = (const float*)d_in[1];
  const float* anch   = (const float*)d_in[2];
  float* out = (float*)d_out;
  char* ws = (char*)d_ws;

  size_t off = 0;
  auto alloc = [&](size_t bytes) {
    size_t o = off;
    off += (bytes + 255) & ~(size_t)255;
    return o;
  };
  size_t o_tks  = alloc((size_t)NROWS * KSEL * 4);
  size_t o_tki  = alloc((size_t)NROWS * KSEL * 4);
  size_t o_fls  = alloc((size_t)BB * NFLAT * 4);
  size_t o_flb  = alloc((size_t)BB * NFLAT * 16);
  size_t need_base = off;
  size_t o_sc = off;                                   // chunked sc goes here
  size_t per_batch_sc = ((size_t)NCLS * AA * 4 + 255) & ~(size_t)255; // 6.92 MB

  int CB = 0;
  for (int cb = BB; cb >= 1; cb >>= 1) {
    if (ws_size >= need_base + (size_t)cb * per_batch_sc) { CB = cb; break; }
  }

  float* tks = (float*)(ws + o_tks);
  int*   tki = (int*)  (ws + o_tki);
  float* fls = (float*)(ws + o_fls);
  float* flb = (float*)(ws + o_flb);
  float* scp = (float*)(ws + o_sc);

  if (CB > 0) {
    for (int b0 = 0; b0 < BB; b0 += CB) {
      hipLaunchKernelGGL(k_sigT, dim3((AA + ATILE - 1) / ATILE, CB), dim3(256), 0,
                         stream, logits, scp, b0);
      hipLaunchKernelGGL(k_row, dim3(NCLS * CB), dim3(512), 0, stream,
                         scp, tks, tki, b0 * NCLS);
    }
  } else {
    hipLaunchKernelGGL(k_topk_direct, dim3(NROWS), dim3(256), 0, stream,
                       logits, tks, tki);
  }
  hipLaunchKernelGGL(k_nms, dim3(NROWS / 4), dim3(256), 0, stream,
                     enc, anch, tks, tki, fls, flb);
  hipLaunchKernelGGL(k_final, dim3(BB), dim3(512), 0, stream,
                     fls, flb, out);
}